// Round 1
// baseline (779.916 us; speedup 1.0000x reference)
//
#include <hip/hip_runtime.h>
#include <math.h>

namespace {
constexpr int TOUT = 32;            // output tile side
constexpr int HALO = 15;            // 16-tap VALID conv halo
constexpr int TIN  = TOUT + HALO;   // 47 input tile side
constexpr int LDA  = TIN + 1;       // 48: padded LDS row stride
constexpr int IMG  = 512;
constexpr int OUTW = IMG - HALO;    // 497

struct GaussWin { float g[16]; };
}

// One block = one 32x32 output tile of one (batch,channel) plane.
// Phase A: stage 47x47 inputs (x255) into LDS, fuse MSE over owned 32x32.
// Phase B: horizontal 16-tap separable pass for 5 signals (x1,x2,x1^2,x2^2,x1x2),
//          4 outputs/thread with float4 LDS reads.
// Phase C: vertical 16-tap pass, 4 consecutive rows/thread (19 reads -> 4 outs),
//          then the SSIM rational map; block-reduce; 2 double atomics.
__global__ __launch_bounds__(256, 3) void ssim_mse_kernel(
    const float* __restrict__ img1,
    const float* __restrict__ img2,
    GaussWin win,
    double* __restrict__ accum)
{
    __shared__ float sA[TIN][LDA];          // 47*48*4 = 9,024 B
    __shared__ float sB[TIN][LDA];          // 9,024 B
    __shared__ float hb[5][TIN][TOUT];      // 5*47*32*4 = 30,080 B
    __shared__ float red[2][4];

    const int tid = threadIdx.x;
    const int ox0 = blockIdx.x * TOUT;
    const int oy0 = blockIdx.y * TOUT;
    const size_t plane_off = (size_t)blockIdx.z * (IMG * IMG);
    const float* __restrict__ p1 = img1 + plane_off;
    const float* __restrict__ p2 = img2 + plane_off;

    float mse_local = 0.0f;

    // ---------------- Phase A: load + MSE ----------------
    for (int i = tid; i < TIN * TIN; i += 256) {
        const int r = i / TIN;
        const int c = i - r * TIN;
        const int gy = oy0 + r;
        const int gx = ox0 + c;
        float a = 0.0f, b = 0.0f;
        if (gy < IMG && gx < IMG) {
            a = p1[gy * IMG + gx];
            b = p2[gy * IMG + gx];
        }
        if (r < TOUT && c < TOUT) {         // owned region: each pixel exactly once
            const float d = a - b;
            mse_local = fmaf(d, d, mse_local);
        }
        sA[r][c] = a * 255.0f;              // SSIM operates in 0..255 range
        sB[r][c] = b * 255.0f;
    }
    __syncthreads();

    // ---------------- Phase B: horizontal conv ----------------
    // items: 47 rows x 8 groups-of-4-columns = 376
    for (int i = tid; i < TIN * 8; i += 256) {
        const int y  = i >> 3;
        const int x0 = (i & 7) * 4;
        float A[20], B[20];
        #pragma unroll
        for (int q = 0; q < 5; ++q) {       // 5 x float4 per input (16B-aligned)
            const float4 a4 = *(const float4*)&sA[y][x0 + 4 * q];
            const float4 b4 = *(const float4*)&sB[y][x0 + 4 * q];
            A[4*q+0] = a4.x; A[4*q+1] = a4.y; A[4*q+2] = a4.z; A[4*q+3] = a4.w;
            B[4*q+0] = b4.x; B[4*q+1] = b4.y; B[4*q+2] = b4.z; B[4*q+3] = b4.w;
        }
        float s1[4]  = {0,0,0,0}, s2[4]  = {0,0,0,0};
        float s11[4] = {0,0,0,0}, s22[4] = {0,0,0,0}, s12[4] = {0,0,0,0};
        #pragma unroll
        for (int k = 0; k < 16; ++k) {
            const float w = win.g[k];
            #pragma unroll
            for (int j = 0; j < 4; ++j) {
                const float a  = A[j + k];
                const float b  = B[j + k];
                const float wa = w * a;
                const float wb = w * b;
                s1[j]  = fmaf(w,  a, s1[j]);
                s2[j]  = fmaf(w,  b, s2[j]);
                s11[j] = fmaf(wa, a, s11[j]);
                s22[j] = fmaf(wb, b, s22[j]);
                s12[j] = fmaf(wa, b, s12[j]);
            }
        }
        *(float4*)&hb[0][y][x0] = make_float4(s1[0],  s1[1],  s1[2],  s1[3]);
        *(float4*)&hb[1][y][x0] = make_float4(s2[0],  s2[1],  s2[2],  s2[3]);
        *(float4*)&hb[2][y][x0] = make_float4(s11[0], s11[1], s11[2], s11[3]);
        *(float4*)&hb[3][y][x0] = make_float4(s22[0], s22[1], s22[2], s22[3]);
        *(float4*)&hb[4][y][x0] = make_float4(s12[0], s12[1], s12[2], s12[3]);
    }
    __syncthreads();

    // ---------------- Phase C: vertical conv + SSIM map ----------------
    float ssim_local = 0.0f;
    {
        const int xo   = tid & 31;
        const int yo0  = (tid >> 5) * 4;    // 0,4,...,28
        const int limx = OUTW - ox0;        // valid xo < limx
        const int limy = OUTW - oy0;

        float m1[4]  = {0,0,0,0}, m2[4]  = {0,0,0,0};
        float c11[4] = {0,0,0,0}, c22[4] = {0,0,0,0}, c12[4] = {0,0,0,0};

        #define VCONV(S, ACC)                                             \
        {                                                                 \
            float v[19];                                                  \
            _Pragma("unroll")                                             \
            for (int k = 0; k < 19; ++k) v[k] = hb[S][yo0 + k][xo];       \
            _Pragma("unroll")                                             \
            for (int j = 0; j < 4; ++j) {                                 \
                _Pragma("unroll")                                         \
                for (int k = 0; k < 16; ++k)                              \
                    ACC[j] = fmaf(win.g[k], v[j + k], ACC[j]);            \
            }                                                             \
        }
        VCONV(0, m1) VCONV(1, m2) VCONV(2, c11) VCONV(3, c22) VCONV(4, c12)
        #undef VCONV

        const float C1v = 6.5025f;    // (0.01*255)^2
        const float C2v = 58.5225f;   // (0.03*255)^2
        #pragma unroll
        for (int j = 0; j < 4; ++j) {
            if (xo < limx && (yo0 + j) < limy) {
                const float mu1 = m1[j], mu2 = m2[j];
                const float mu1sq = mu1 * mu1;
                const float mu2sq = mu2 * mu2;
                const float mu12  = mu1 * mu2;
                const float sg1  = c11[j] - mu1sq;
                const float sg2  = c22[j] - mu2sq;
                const float sg12 = c12[j] - mu12;
                const float num = (2.0f * mu12 + C1v) * (2.0f * sg12 + C2v);
                const float den = (mu1sq + mu2sq + C1v) * (sg1 + sg2 + C2v);
                ssim_local += num / den;
            }
        }
    }

    // ---------------- Reduction ----------------
    #pragma unroll
    for (int off = 32; off > 0; off >>= 1) {
        mse_local  += __shfl_down(mse_local,  off, 64);
        ssim_local += __shfl_down(ssim_local, off, 64);
    }
    const int wave = tid >> 6;
    if ((tid & 63) == 0) { red[0][wave] = mse_local; red[1][wave] = ssim_local; }
    __syncthreads();
    if (tid == 0) {
        const double m = (double)red[0][0] + (double)red[0][1]
                       + (double)red[0][2] + (double)red[0][3];
        const double s = (double)red[1][0] + (double)red[1][1]
                       + (double)red[1][2] + (double)red[1][3];
        atomicAdd(&accum[0], m);
        atomicAdd(&accum[1], s);
    }
}

__global__ void finalize_kernel(const double* __restrict__ accum,
                                float* __restrict__ out)
{
    const double n_mse  = 25165824.0;   // 32*3*512*512
    const double n_ssim = 23712864.0;   // 32*3*497*497
    const double mse  = accum[0] / n_mse;
    const double ssim = accum[1] / n_ssim;
    out[0] = (float)(0.7 * mse + 0.3 * (1.0 - ssim));
}

extern "C" void kernel_launch(void* const* d_in, const int* in_sizes, int n_in,
                              void* d_out, int out_size, void* d_ws, size_t ws_size,
                              hipStream_t stream) {
    const float* img1 = (const float*)d_in[0];
    const float* img2 = (const float*)d_in[1];
    float* out = (float*)d_out;
    double* accum = (double*)d_ws;

    hipMemsetAsync(d_ws, 0, 2 * sizeof(double), stream);

    GaussWin win;
    {
        double g[16], s = 0.0;
        for (int i = 0; i < 16; ++i) {
            const double c = (double)i - 7.5;
            g[i] = exp(-(c * c) / 4.5);
            s += g[i];
        }
        for (int i = 0; i < 16; ++i) win.g[i] = (float)(g[i] / s);
    }

    dim3 grid(16, 16, 96);   // 16x16 tiles of 497x497, 96 = 32*3 planes
    ssim_mse_kernel<<<grid, dim3(256), 0, stream>>>(img1, img2, win, accum);
    finalize_kernel<<<1, 1, 0, stream>>>(accum, out);
}

// Round 2
// 753.461 us; speedup vs baseline: 1.0351x; 1.0351x over previous
//
#include <hip/hip_runtime.h>
#include <math.h>

namespace {
constexpr int TOUT = 32;            // output tile side
constexpr int HALO = 15;            // 16-tap VALID conv halo
constexpr int TIN  = TOUT + HALO;   // 47 rows of horizontal-conv output
constexpr int HLD  = 36;            // hb row stride (floats): 16B-aligned, permutation banking
constexpr int IMG  = 512;
constexpr int OUTW = IMG - HALO;    // 497

struct GaussWin { float g[16]; };
}

// One block = one 32x32 output tile of one (batch,channel) plane.
// Phase AB (fused): 188 threads each own an 8-output row segment. Load 23
//   raw floats per image straight into registers (vectorized fast path),
//   fuse MSE over the owned 8 pixels, run the 16-tap horizontal conv for
//   FOUR signals (a, b, a^2+b^2, a*b -- sigma1^2+sigma2^2 only ever appears
//   as a sum in SSIM), write hb[4][47][36] to LDS. No input staging in LDS.
// Phase C: vertical 16-tap pass (4 rows/thread, 19 reads -> 4 outputs per
//   signal), SSIM rational map with 255-scale folded into C1/C2, reduce.
__global__ __launch_bounds__(256, 4) void ssim_mse_kernel(
    const float* __restrict__ img1,
    const float* __restrict__ img2,
    GaussWin win,
    double* __restrict__ accum)
{
    __shared__ float hb[4][TIN][HLD];   // 4*47*36*4 = 27,072 B
    __shared__ float red[2][4];

    const int tid = threadIdx.x;
    const int ox0 = blockIdx.x * TOUT;
    const int oy0 = blockIdx.y * TOUT;
    const size_t plane_off = (size_t)blockIdx.z * (IMG * IMG);
    const float* __restrict__ p1 = img1 + plane_off;
    const float* __restrict__ p2 = img2 + plane_off;

    float mse_local = 0.0f;

    // ---------------- Phase AB: load + MSE + horizontal conv ----------------
    if (tid < TIN * 4) {
        const int r  = tid >> 2;        // 0..46
        const int s  = tid & 3;         // segment: 8 outputs each
        const int gy = oy0 + r;
        const int c0 = ox0 + 8 * s;

        float A[23], B[23];
        const bool fast = (gy < IMG) & (c0 + 23 <= IMG);
        if (fast) {
            const float* __restrict__ pa = p1 + (size_t)gy * IMG + c0;
            const float* __restrict__ pb = p2 + (size_t)gy * IMG + c0;
            #pragma unroll
            for (int q = 0; q < 5; ++q) {
                const float4 va = *(const float4*)(pa + 4 * q);
                const float4 vb = *(const float4*)(pb + 4 * q);
                A[4*q+0] = va.x; A[4*q+1] = va.y; A[4*q+2] = va.z; A[4*q+3] = va.w;
                B[4*q+0] = vb.x; B[4*q+1] = vb.y; B[4*q+2] = vb.z; B[4*q+3] = vb.w;
            }
            const float2 ta = *(const float2*)(pa + 20);
            const float2 tb = *(const float2*)(pb + 20);
            A[20] = ta.x; A[21] = ta.y; A[22] = pa[22];
            B[20] = tb.x; B[21] = tb.y; B[22] = pb[22];
        } else {
            // edge tiles: clamped scalar loads; garbage only lands in hb
            // entries that phase C masks out (valid outputs need only
            // in-bounds inputs).
            const int gyc = gy < IMG ? gy : (IMG - 1);
            const float* __restrict__ pa = p1 + (size_t)gyc * IMG;
            const float* __restrict__ pb = p2 + (size_t)gyc * IMG;
            #pragma unroll
            for (int k = 0; k < 23; ++k) {
                const int gx = (c0 + k) < IMG ? (c0 + k) : (IMG - 1);
                A[k] = pa[gx];
                B[k] = pb[gx];
            }
        }

        // MSE over the owned 8 pixels (always in-bounds: grid tiles 512 exactly)
        if (r < TOUT) {
            #pragma unroll
            for (int j = 0; j < 8; ++j) {
                const float d = A[j] - B[j];
                mse_local = fmaf(d, d, mse_local);
            }
        }

        // pass 1: linear signals
        float s1[8] = {0,0,0,0,0,0,0,0}, s2[8] = {0,0,0,0,0,0,0,0};
        #pragma unroll
        for (int k = 0; k < 16; ++k) {
            const float w = win.g[k];
            #pragma unroll
            for (int j = 0; j < 8; ++j) {
                s1[j] = fmaf(w, A[j + k], s1[j]);
                s2[j] = fmaf(w, B[j + k], s2[j]);
            }
        }
        // in-place transform: A[i] := a^2+b^2, B[i] := a*b
        #pragma unroll
        for (int i = 0; i < 23; ++i) {
            const float a = A[i], b = B[i];
            A[i] = fmaf(a, a, b * b);
            B[i] = a * b;
        }
        // pass 2: quadratic signals
        float sq[8] = {0,0,0,0,0,0,0,0}, sx[8] = {0,0,0,0,0,0,0,0};
        #pragma unroll
        for (int k = 0; k < 16; ++k) {
            const float w = win.g[k];
            #pragma unroll
            for (int j = 0; j < 8; ++j) {
                sq[j] = fmaf(w, A[j + k], sq[j]);
                sx[j] = fmaf(w, B[j + k], sx[j]);
            }
        }

        const int x0 = 8 * s;
        *(float4*)&hb[0][r][x0]     = make_float4(s1[0], s1[1], s1[2], s1[3]);
        *(float4*)&hb[0][r][x0 + 4] = make_float4(s1[4], s1[5], s1[6], s1[7]);
        *(float4*)&hb[1][r][x0]     = make_float4(s2[0], s2[1], s2[2], s2[3]);
        *(float4*)&hb[1][r][x0 + 4] = make_float4(s2[4], s2[5], s2[6], s2[7]);
        *(float4*)&hb[2][r][x0]     = make_float4(sq[0], sq[1], sq[2], sq[3]);
        *(float4*)&hb[2][r][x0 + 4] = make_float4(sq[4], sq[5], sq[6], sq[7]);
        *(float4*)&hb[3][r][x0]     = make_float4(sx[0], sx[1], sx[2], sx[3]);
        *(float4*)&hb[3][r][x0 + 4] = make_float4(sx[4], sx[5], sx[6], sx[7]);
    }
    __syncthreads();

    // ---------------- Phase C: vertical conv + SSIM map ----------------
    float ssim_local = 0.0f;
    {
        const int xo   = tid & 31;
        const int yo0  = (tid >> 5) * 4;    // 0,4,...,28
        const int limx = OUTW - ox0;        // valid xo < limx
        const int limy = OUTW - oy0;

        float m1[4]  = {0,0,0,0}, m2[4]  = {0,0,0,0};
        float mq[4]  = {0,0,0,0}, mx[4]  = {0,0,0,0};

        #define VCONV(S, ACC)                                             \
        {                                                                 \
            float v[19];                                                  \
            _Pragma("unroll")                                             \
            for (int k = 0; k < 19; ++k) v[k] = hb[S][yo0 + k][xo];       \
            _Pragma("unroll")                                             \
            for (int j = 0; j < 4; ++j) {                                 \
                _Pragma("unroll")                                         \
                for (int k = 0; k < 16; ++k)                              \
                    ACC[j] = fmaf(win.g[k], v[j + k], ACC[j]);            \
            }                                                             \
        }
        VCONV(0, m1) VCONV(1, m2) VCONV(2, mq) VCONV(3, mx)
        #undef VCONV

        // 255-scale folded in: C1/255^2 = 1e-4, C2/255^2 = 9e-4
        const float C1u = 1.0e-4f;
        const float C2u = 9.0e-4f;
        #pragma unroll
        for (int j = 0; j < 4; ++j) {
            if (xo < limx && (yo0 + j) < limy) {
                const float mu1  = m1[j], mu2 = m2[j];
                const float mu12 = mu1 * mu2;
                const float musq = fmaf(mu1, mu1, mu2 * mu2);
                const float sgq  = mq[j] - musq;   // sigma1^2 + sigma2^2
                const float sg12 = mx[j] - mu12;
                const float num = fmaf(2.0f, mu12, C1u) * fmaf(2.0f, sg12, C2u);
                const float den = (musq + C1u) * (sgq + C2u);
                ssim_local += num / den;
            }
        }
    }

    // ---------------- Reduction ----------------
    #pragma unroll
    for (int off = 32; off > 0; off >>= 1) {
        mse_local  += __shfl_down(mse_local,  off, 64);
        ssim_local += __shfl_down(ssim_local, off, 64);
    }
    const int wave = tid >> 6;
    if ((tid & 63) == 0) { red[0][wave] = mse_local; red[1][wave] = ssim_local; }
    __syncthreads();
    if (tid == 0) {
        const double m = (double)red[0][0] + (double)red[0][1]
                       + (double)red[0][2] + (double)red[0][3];
        const double s = (double)red[1][0] + (double)red[1][1]
                       + (double)red[1][2] + (double)red[1][3];
        atomicAdd(&accum[0], m);
        atomicAdd(&accum[1], s);
    }
}

__global__ void finalize_kernel(const double* __restrict__ accum,
                                float* __restrict__ out)
{
    const double n_mse  = 25165824.0;   // 32*3*512*512
    const double n_ssim = 23712864.0;   // 32*3*497*497
    const double mse  = accum[0] / n_mse;
    const double ssim = accum[1] / n_ssim;
    out[0] = (float)(0.7 * mse + 0.3 * (1.0 - ssim));
}

extern "C" void kernel_launch(void* const* d_in, const int* in_sizes, int n_in,
                              void* d_out, int out_size, void* d_ws, size_t ws_size,
                              hipStream_t stream) {
    const float* img1 = (const float*)d_in[0];
    const float* img2 = (const float*)d_in[1];
    float* out = (float*)d_out;
    double* accum = (double*)d_ws;

    hipMemsetAsync(d_ws, 0, 2 * sizeof(double), stream);

    GaussWin win;
    {
        double g[16], s = 0.0;
        for (int i = 0; i < 16; ++i) {
            const double c = (double)i - 7.5;
            g[i] = exp(-(c * c) / 4.5);
            s += g[i];
        }
        for (int i = 0; i < 16; ++i) win.g[i] = (float)(g[i] / s);
    }

    dim3 grid(16, 16, 96);   // 16x16 tiles of 497x497, 96 = 32*3 planes
    ssim_mse_kernel<<<grid, dim3(256), 0, stream>>>(img1, img2, win, accum);
    finalize_kernel<<<1, 1, 0, stream>>>(accum, out);
}

// Round 3
// 417.398 us; speedup vs baseline: 1.8685x; 1.8051x over previous
//
#include <hip/hip_runtime.h>
#include <math.h>

namespace {
constexpr int TOUT = 32;            // output tile side
constexpr int HALO = 15;            // 16-tap VALID conv halo
constexpr int TIN  = TOUT + HALO;   // 47 rows of horizontal-conv output
constexpr int HLD  = 36;            // hb row stride (floats)
constexpr int IMG  = 512;
constexpr int OUTW = IMG - HALO;    // 497
constexpr int NBLK = 16 * 16 * 96;  // 24576 blocks

struct GaussWin { float g[16]; };
}

// One block = one 32x32 output tile of one (batch,channel) plane.
// Phase AB (fused): 188 threads each own an 8-output row segment: load 23
//   floats/image into registers, fuse MSE, 16-tap horizontal conv for 4
//   signals (a, b, a^2+b^2, a*b), write hb[4][47][36] to LDS.
// Phase C: vertical 16-tap pass (4 rows/thread), SSIM rational map
//   (255-scale folded into C1/C2), block reduce.
// Tail: NO same-address atomics (R2 showed 49k f64 atomics to one line
//   serialize at ~13 ns each = the entire 635 us) -- write per-block
//   double2 partial to a private d_ws slot; reduce_kernel sums them.
template <bool TWO_STAGE>
__global__ __launch_bounds__(256, 4) void ssim_mse_kernel(
    const float* __restrict__ img1,
    const float* __restrict__ img2,
    GaussWin win,
    double2* __restrict__ partial,   // TWO_STAGE: one slot per block
    double*  __restrict__ accum)     // fallback: atomic accumulators
{
    __shared__ float hb[4][TIN][HLD];   // 27,072 B
    __shared__ float red[2][4];

    const int tid = threadIdx.x;
    const int ox0 = blockIdx.x * TOUT;
    const int oy0 = blockIdx.y * TOUT;
    const size_t plane_off = (size_t)blockIdx.z * (IMG * IMG);
    const float* __restrict__ p1 = img1 + plane_off;
    const float* __restrict__ p2 = img2 + plane_off;

    float mse_local = 0.0f;

    // ---------------- Phase AB: load + MSE + horizontal conv ----------------
    if (tid < TIN * 4) {
        const int r  = tid >> 2;        // 0..46
        const int s  = tid & 3;         // segment: 8 outputs each
        const int gy = oy0 + r;
        const int c0 = ox0 + 8 * s;

        float A[23], B[23];
        const bool fast = (gy < IMG) & (c0 + 23 <= IMG);
        if (fast) {
            const float* __restrict__ pa = p1 + (size_t)gy * IMG + c0;
            const float* __restrict__ pb = p2 + (size_t)gy * IMG + c0;
            #pragma unroll
            for (int q = 0; q < 5; ++q) {
                const float4 va = *(const float4*)(pa + 4 * q);
                const float4 vb = *(const float4*)(pb + 4 * q);
                A[4*q+0] = va.x; A[4*q+1] = va.y; A[4*q+2] = va.z; A[4*q+3] = va.w;
                B[4*q+0] = vb.x; B[4*q+1] = vb.y; B[4*q+2] = vb.z; B[4*q+3] = vb.w;
            }
            const float2 ta = *(const float2*)(pa + 20);
            const float2 tb = *(const float2*)(pb + 20);
            A[20] = ta.x; A[21] = ta.y; A[22] = pa[22];
            B[20] = tb.x; B[21] = tb.y; B[22] = pb[22];
        } else {
            const int gyc = gy < IMG ? gy : (IMG - 1);
            const float* __restrict__ pa = p1 + (size_t)gyc * IMG;
            const float* __restrict__ pb = p2 + (size_t)gyc * IMG;
            #pragma unroll
            for (int k = 0; k < 23; ++k) {
                const int gx = (c0 + k) < IMG ? (c0 + k) : (IMG - 1);
                A[k] = pa[gx];
                B[k] = pb[gx];
            }
        }

        if (r < TOUT) {
            #pragma unroll
            for (int j = 0; j < 8; ++j) {
                const float d = A[j] - B[j];
                mse_local = fmaf(d, d, mse_local);
            }
        }

        float s1[8] = {0,0,0,0,0,0,0,0}, s2[8] = {0,0,0,0,0,0,0,0};
        #pragma unroll
        for (int k = 0; k < 16; ++k) {
            const float w = win.g[k];
            #pragma unroll
            for (int j = 0; j < 8; ++j) {
                s1[j] = fmaf(w, A[j + k], s1[j]);
                s2[j] = fmaf(w, B[j + k], s2[j]);
            }
        }
        #pragma unroll
        for (int i = 0; i < 23; ++i) {
            const float a = A[i], b = B[i];
            A[i] = fmaf(a, a, b * b);
            B[i] = a * b;
        }
        float sq[8] = {0,0,0,0,0,0,0,0}, sx[8] = {0,0,0,0,0,0,0,0};
        #pragma unroll
        for (int k = 0; k < 16; ++k) {
            const float w = win.g[k];
            #pragma unroll
            for (int j = 0; j < 8; ++j) {
                sq[j] = fmaf(w, A[j + k], sq[j]);
                sx[j] = fmaf(w, B[j + k], sx[j]);
            }
        }

        const int x0 = 8 * s;
        *(float4*)&hb[0][r][x0]     = make_float4(s1[0], s1[1], s1[2], s1[3]);
        *(float4*)&hb[0][r][x0 + 4] = make_float4(s1[4], s1[5], s1[6], s1[7]);
        *(float4*)&hb[1][r][x0]     = make_float4(s2[0], s2[1], s2[2], s2[3]);
        *(float4*)&hb[1][r][x0 + 4] = make_float4(s2[4], s2[5], s2[6], s2[7]);
        *(float4*)&hb[2][r][x0]     = make_float4(sq[0], sq[1], sq[2], sq[3]);
        *(float4*)&hb[2][r][x0 + 4] = make_float4(sq[4], sq[5], sq[6], sq[7]);
        *(float4*)&hb[3][r][x0]     = make_float4(sx[0], sx[1], sx[2], sx[3]);
        *(float4*)&hb[3][r][x0 + 4] = make_float4(sx[4], sx[5], sx[6], sx[7]);
    }
    __syncthreads();

    // ---------------- Phase C: vertical conv + SSIM map ----------------
    float ssim_local = 0.0f;
    {
        const int xo   = tid & 31;
        const int yo0  = (tid >> 5) * 4;    // 0,4,...,28
        const int limx = OUTW - ox0;
        const int limy = OUTW - oy0;

        float m1[4] = {0,0,0,0}, m2[4] = {0,0,0,0};
        float mq[4] = {0,0,0,0}, mx[4] = {0,0,0,0};

        #define VCONV(S, ACC)                                             \
        {                                                                 \
            float v[19];                                                  \
            _Pragma("unroll")                                             \
            for (int k = 0; k < 19; ++k) v[k] = hb[S][yo0 + k][xo];       \
            _Pragma("unroll")                                             \
            for (int j = 0; j < 4; ++j) {                                 \
                _Pragma("unroll")                                         \
                for (int k = 0; k < 16; ++k)                              \
                    ACC[j] = fmaf(win.g[k], v[j + k], ACC[j]);            \
            }                                                             \
        }
        VCONV(0, m1) VCONV(1, m2) VCONV(2, mq) VCONV(3, mx)
        #undef VCONV

        const float C1u = 1.0e-4f;   // (0.01*255)^2 / 255^2
        const float C2u = 9.0e-4f;   // (0.03*255)^2 / 255^2
        #pragma unroll
        for (int j = 0; j < 4; ++j) {
            if (xo < limx && (yo0 + j) < limy) {
                const float mu1  = m1[j], mu2 = m2[j];
                const float mu12 = mu1 * mu2;
                const float musq = fmaf(mu1, mu1, mu2 * mu2);
                const float sgq  = mq[j] - musq;
                const float sg12 = mx[j] - mu12;
                const float num = fmaf(2.0f, mu12, C1u) * fmaf(2.0f, sg12, C2u);
                const float den = (musq + C1u) * (sgq + C2u);
                ssim_local += num / den;
            }
        }
    }

    // ---------------- Block reduction + partial write ----------------
    #pragma unroll
    for (int off = 32; off > 0; off >>= 1) {
        mse_local  += __shfl_down(mse_local,  off, 64);
        ssim_local += __shfl_down(ssim_local, off, 64);
    }
    const int wave = tid >> 6;
    if ((tid & 63) == 0) { red[0][wave] = mse_local; red[1][wave] = ssim_local; }
    __syncthreads();
    if (tid == 0) {
        const double m = (double)red[0][0] + (double)red[0][1]
                       + (double)red[0][2] + (double)red[0][3];
        const double s = (double)red[1][0] + (double)red[1][1]
                       + (double)red[1][2] + (double)red[1][3];
        if (TWO_STAGE) {
            const int bid = (int)blockIdx.x
                          + 16 * ((int)blockIdx.y + 16 * (int)blockIdx.z);
            partial[bid] = make_double2(m, s);
        } else {
            atomicAdd(&accum[0], m);
            atomicAdd(&accum[1], s);
        }
    }
}

// Single block, 1024 threads: 24576 partials = 1024 x 24 exactly.
__global__ __launch_bounds__(1024) void reduce_kernel(
    const double2* __restrict__ partial,
    float* __restrict__ out)
{
    __shared__ double sm[16], ss[16];
    const int tid = threadIdx.x;
    double m = 0.0, s = 0.0;
    #pragma unroll
    for (int k = 0; k < 24; ++k) {
        const double2 p = partial[tid + 1024 * k];
        m += p.x; s += p.y;
    }
    #pragma unroll
    for (int off = 32; off > 0; off >>= 1) {
        m += __shfl_down(m, off, 64);
        s += __shfl_down(s, off, 64);
    }
    if ((tid & 63) == 0) { sm[tid >> 6] = m; ss[tid >> 6] = s; }
    __syncthreads();
    if (tid == 0) {
        double M = 0.0, S = 0.0;
        #pragma unroll
        for (int w = 0; w < 16; ++w) { M += sm[w]; S += ss[w]; }
        const double mse  = M / 25165824.0;   // 32*3*512*512
        const double ssim = S / 23712864.0;   // 32*3*497*497
        out[0] = (float)(0.7 * mse + 0.3 * (1.0 - ssim));
    }
}

__global__ void finalize_kernel(const double* __restrict__ accum,
                                float* __restrict__ out)
{
    const double mse  = accum[0] / 25165824.0;
    const double ssim = accum[1] / 23712864.0;
    out[0] = (float)(0.7 * mse + 0.3 * (1.0 - ssim));
}

extern "C" void kernel_launch(void* const* d_in, const int* in_sizes, int n_in,
                              void* d_out, int out_size, void* d_ws, size_t ws_size,
                              hipStream_t stream) {
    const float* img1 = (const float*)d_in[0];
    const float* img2 = (const float*)d_in[1];
    float* out = (float*)d_out;

    GaussWin win;
    {
        double g[16], s = 0.0;
        for (int i = 0; i < 16; ++i) {
            const double c = (double)i - 7.5;
            g[i] = exp(-(c * c) / 4.5);
            s += g[i];
        }
        for (int i = 0; i < 16; ++i) win.g[i] = (float)(g[i] / s);
    }

    dim3 grid(16, 16, 96);   // 16x16 tiles of 497x497, 96 = 32*3 planes
    if (ws_size >= (size_t)NBLK * sizeof(double2)) {
        double2* partial = (double2*)d_ws;
        ssim_mse_kernel<true><<<grid, dim3(256), 0, stream>>>(
            img1, img2, win, partial, nullptr);
        reduce_kernel<<<1, dim3(1024), 0, stream>>>(partial, out);
    } else {
        double* accum = (double*)d_ws;
        hipMemsetAsync(d_ws, 0, 2 * sizeof(double), stream);
        ssim_mse_kernel<false><<<grid, dim3(256), 0, stream>>>(
            img1, img2, win, nullptr, accum);
        finalize_kernel<<<1, 1, 0, stream>>>(accum, out);
    }
}